// Round 7
// baseline (568.176 us; speedup 1.0000x reference)
//
#include <hip/hip_runtime.h>

// ---------------------------------------------------------------------------
// BERT layer (attn + top-1 MoE FFN) for MI355X / gfx950.
// B=16 S=512 H=1024 I=4096 NH=16 DH=64 E=8.  bf16 MFMA (16x16x32), fp32 accum.
// R7: gemm_bt -> 4-slot LDS ring (64KB) + REGISTER frag double-buffer: each
// iter stages tile t+3 and ds_reads frags(t+1) BEFORE the MFMA cluster on
// frags(t), so LDS latency hides under MFMA (compiler lgkmcnt waits only on
// last iter's reads).  Counted vmcnt(4), raw s_barrier, literal slot/parity.
// ---------------------------------------------------------------------------

typedef __attribute__((ext_vector_type(4))) float f32x4;
typedef __attribute__((ext_vector_type(8))) short s8v;   // 8 x bf16 bits
typedef __attribute__((ext_vector_type(4))) short s4v;   // 4 x bf16 bits
typedef unsigned short u16;

#define DEV static __device__ __forceinline__

DEV u16 f2bf(float f){
  union { float f; unsigned u; } v; v.f = f;
  unsigned r = v.u + 0x7fffu + ((v.u >> 16) & 1u);   // RNE
  return (u16)(r >> 16);
}

DEV f32x4 mfma16(s8v a, s8v b, f32x4 c){
  return __builtin_amdgcn_mfma_f32_16x16x32_bf16(a, b, c, 0, 0, 0);
}

DEV float wave_sum(float s){
#pragma unroll
  for (int o = 1; o < 64; o <<= 1) s += __shfl_xor(s, o);
  return s;
}

#define ASYNC_COPY16(g, l) \
  __builtin_amdgcn_global_load_lds((const __attribute__((address_space(1))) void*)(g), \
                                   (__attribute__((address_space(3))) void*)(l), 16, 0, 0)

// ---------------------------------------------------------------------------
// fp32 [n*8] -> bf16
__global__ __launch_bounds__(256) void cvt_bf16(const float* __restrict__ in,
                                                u16* __restrict__ out)
{
  const size_t i = ((size_t)blockIdx.x * 256 + threadIdx.x) * 8;
  f32x4 a = *(const f32x4*)&in[i];
  f32x4 b = *(const f32x4*)&in[i + 4];
  s8v o;
#pragma unroll
  for (int j = 0; j < 4; ++j){ o[j] = (short)f2bf(a[j]); o[4 + j] = (short)f2bf(b[j]); }
  *(s8v*)&out[i] = o;
}

// fp32 [R][C] -> bf16 [C][R]   (batched via blockIdx.z, stride R*C)
__global__ __launch_bounds__(256) void transpose_w(const float* __restrict__ in,
                                                   u16* __restrict__ out, int R, int C)
{
  __shared__ float t[64][65];
  const size_t bs = (size_t)blockIdx.z * R * (size_t)C;
  in += bs; out += bs;
  const int c0 = blockIdx.x * 64, r0 = blockIdx.y * 64;
  const int tx = threadIdx.x & 63, ty = threadIdx.x >> 6;   // 64 x 4
#pragma unroll
  for (int j = 0; j < 64; j += 4) t[ty + j][tx] = in[(size_t)(r0 + ty + j) * C + c0 + tx];
  __syncthreads();
#pragma unroll
  for (int j = 0; j < 64; j += 4) out[(size_t)(c0 + ty + j) * R + r0 + tx] = f2bf(t[tx][ty + j]);
}

// ---------------------------------------------------------------------------
// C = A[M,K](bf16) * Bt[N,K]^T(bf16) + bias.
// Tile 128x128, 4 waves (2Mx2N, wave-out 64x64, acc[4][4]), BK=32.
// 4-slot LDS ring (64KB) + register frag double-buffer (pipeline depth:
// LDS 3 tiles ahead, regs 1 tile ahead).  Raw s_barrier + counted vmcnt(4).
// LDS swizzle: stored[row][seg] = global[row][seg ^ ((row>>1)&3)], 16B segs.
// nk = K/32 must be % 4 == 0 and >= 8 (K=1024 -> 32, K=4096 -> 128).
// MODE 1: gelu->bf16 out   2: fp32 out + residual
// MODE 4: fused QKV epilogue (cols 0-1023 -> outp, 1024-2047 -> out2,
//         2048-3071 -> vt-scatter to out3); bias is 3072-wide concat.
// SWZ: bijective XCD swizzle (requires nwg % 8 == 0; guarded).
template<int MODE, bool SWZ>
__global__ __launch_bounds__(256, 2) void gemm_bt(
    const u16* __restrict__ A, const u16* __restrict__ Bt,
    const float* __restrict__ bias, void* __restrict__ outp,
    const float* __restrict__ resid, int M, int N, int K,
    const int* __restrict__ choice,
    long aBatch, long outBatch, long residBatch, long btExpert, long biasExpert,
    void* __restrict__ out2, void* __restrict__ out3)
{
  int bx, by, bz;
  if (SWZ){
    const int nx = gridDim.x, ny = gridDim.y;
    const int nwg = nx * ny * gridDim.z;
    int id = blockIdx.x + nx * (blockIdx.y + ny * blockIdx.z);
    if ((nwg & 7) == 0){ const int q = nwg >> 3; id = (id & 7) * q + (id >> 3); }
    bx = id % nx; const int r2 = id / nx; by = r2 % ny; bz = r2 / ny;
  } else {
    bx = blockIdx.x; by = blockIdx.y; bz = blockIdx.z;
  }
  const int z = bz;
  if (choice){
    const int e = choice[z];
    Bt   += (size_t)e * btExpert;
    bias += (size_t)e * biasExpert;
  }
  A += (size_t)z * aBatch;

  const int tid = threadIdx.x;
  const int lane = tid & 63, wid = tid >> 6;
  const int hi = lane >> 4, l15 = lane & 15;
  const int wr = wid >> 1, wc = wid & 1;
  const long row0 = (long)bx * 128;
  const long col0 = (long)by * 128;

  __shared__ __align__(16) u16 lA[4][128 * 32];   // 32 KB
  __shared__ __align__(16) u16 lB[4][128 * 32];   // 32 KB

  f32x4 acc[4][4];
#pragma unroll
  for (int i = 0; i < 4; ++i)
#pragma unroll
    for (int j = 0; j < 4; ++j) acc[i][j] = f32x4{0.f, 0.f, 0.f, 0.f};

  // staging: each tile = 512 16B slots (2/thread); row = j*64 + (tid>>2),
  // seg = tid&3; swizzle key (row>>1)&3 = (tid>>3)&3 (j*64 doesn't affect it).
  const int r0 = tid >> 2;
  const int scol = (((tid & 3) ^ ((tid >> 3) & 3)) << 3);   // pre-swizzled src
  const u16* pA[2]; const u16* pB[2];
#pragma unroll
  for (int j = 0; j < 2; ++j){
    pA[j] = A  + (row0 + j * 64 + r0) * (size_t)K + scol;
    pB[j] = Bt + (col0 + j * 64 + r0) * (size_t)K + scol;
  }

#define GSTAGE(S_) do { \
  _Pragma("unroll") \
  for (int j = 0; j < 2; ++j) ASYNC_COPY16(pA[j], &lA[S_][(j * 256 + tid) * 8]); \
  _Pragma("unroll") \
  for (int j = 0; j < 2; ++j) ASYNC_COPY16(pB[j], &lB[S_][(j * 256 + tid) * 8]); \
  _Pragma("unroll") \
  for (int j = 0; j < 2; ++j){ pA[j] += 32; pB[j] += 32; } \
} while (0)

  // fragment bases (swizzled read): key = ((wr*64+mi*16+l15)>>1)&3 = (l15>>1)&3
  const int rkey = (l15 >> 1) & 3;
  const int baseA = (wr * 64 + l15) * 32 + ((hi ^ rkey) << 3);
  const int baseB = (wc * 64 + l15) * 32 + ((hi ^ rkey) << 3);

  s8v fA[2][4], fB[2][4];                 // register frag double-buffer

#define LOADFRAGS(P_, S_) do { \
  _Pragma("unroll") \
  for (int mi = 0; mi < 4; ++mi) fA[P_][mi] = *(const s8v*)&lA[S_][baseA + mi * 512]; \
  _Pragma("unroll") \
  for (int ni = 0; ni < 4; ++ni) fB[P_][ni] = *(const s8v*)&lB[S_][baseB + ni * 512]; \
} while (0)

// one K-step for tile t (frag parity P_): wait tile t+1 loads (counted),
// barrier (slot of t-1 free for all waves; t+1 visible), stage tile t+3,
// ds_read frags(t+1) -- latency hides under MFMA(t) below (compiler's lgkm
// wait before MFMA covers only LAST iter's reads, already complete).
#define ITER(VM_, DOSTAGE_, S3_, DOREAD_, S1_, P_) do { \
  asm volatile("s_waitcnt vmcnt(" VM_ ")" ::: "memory"); \
  __builtin_amdgcn_s_barrier(); \
  __builtin_amdgcn_sched_barrier(0); \
  if (DOSTAGE_) GSTAGE(S3_); \
  if (DOREAD_) LOADFRAGS((P_) ^ 1, S1_); \
  __builtin_amdgcn_s_setprio(1); \
  _Pragma("unroll") \
  for (int mi = 0; mi < 4; ++mi) \
    _Pragma("unroll") \
    for (int ni = 0; ni < 4; ++ni) \
      acc[mi][ni] = mfma16(fA[P_][mi], fB[P_][ni], acc[mi][ni]); \
  __builtin_amdgcn_s_setprio(0); \
} while (0)

  const int nk = K >> 5;                  // 32 or 128 (nk % 4 == 0, >= 8)
  GSTAGE(0); GSTAGE(1); GSTAGE(2);        // tiles 0,1,2 in flight (12 loads)
  asm volatile("s_waitcnt vmcnt(8)" ::: "memory");   // tile 0 landed
  __builtin_amdgcn_s_barrier();
  __builtin_amdgcn_sched_barrier(0);
  LOADFRAGS(0, 0);                        // frags(0), parity 0

  for (int t = 0; t < nk - 4; t += 4){    // tiles t..t+3; stages t+3..t+6
    ITER("4", 1, 3, 1, 1, 0);
    ITER("4", 1, 0, 1, 2, 1);
    ITER("4", 1, 1, 1, 3, 0);
    ITER("4", 1, 2, 1, 0, 1);
  }
  // tail: tiles nk-4..nk-1 (slots 0..3); only one stage left (tile nk-1)
  ITER("4", 1, 3, 1, 1, 0);
  ITER("4", 0, 0, 1, 2, 1);
  ITER("0", 0, 0, 1, 3, 0);
  ITER("0", 0, 0, 0, 0, 1);
#undef ITER
#undef LOADFRAGS
#undef GSTAGE

#pragma unroll
  for (int mi = 0; mi < 4; ++mi){
    const long rowb = row0 + wr * 64 + mi * 16 + hi * 4;
#pragma unroll
    for (int ni = 0; ni < 4; ++ni){
      const long col = col0 + wc * 64 + ni * 16 + l15;
      const float bv = bias[col];
#pragma unroll
      for (int r = 0; r < 4; ++r){
        const long row = rowb + r;
        float v = acc[mi][ni][r] + bv;
        if (MODE == 2){
          float* o = (float*)outp + (size_t)z * outBatch;
          const float* rs = resid + (size_t)z * residBatch;
          o[row * N + col] = v + rs[row * N + col];
        } else if (MODE == 1){
          u16* o = (u16*)outp + (size_t)z * outBatch;
          const float gv = 0.5f * v * (1.0f + erff(v * 0.70710678118654752f));
          o[row * N + col] = f2bf(gv);
        } else if (MODE == 4){          // fused QKV
          const int seg = (int)(col >> 10), lc = (int)(col & 1023);
          const u16 bv16 = f2bf(v);
          if (seg == 0)      ((u16*)outp)[row * 1024 + lc] = bv16;
          else if (seg == 1) ((u16*)out2)[row * 1024 + lc] = bv16;
          else {
            const int bb = (int)(row >> 9), ss = (int)(row & 511);
            const int hh = lc >> 6, dd = lc & 63;
            ((u16*)out3)[(((size_t)(bb * 16 + hh)) * 64 + dd) * 512 + ss] = bv16;
          }
        }
      }
    }
  }
}

// ---------------------------------------------------------------------------
// Flash attention, swapped form (S^T = K*Q^T; softmax state lane-local, q=l15).
// Block = (b, h, 128 q rows).  4 waves x 2 q-tiles (ILP-2 softmax chains).
__global__ __launch_bounds__(256) void attn_fwd(
    const u16* __restrict__ qb, const u16* __restrict__ kb,
    const u16* __restrict__ vt, u16* __restrict__ ctx)
{
  const int tid = threadIdx.x;
  const int lane = tid & 63, wid = tid >> 6;
  const int hi = lane >> 4, l15 = lane & 15;
  const int h = blockIdx.y, b = blockIdx.z;
  const int q0 = blockIdx.x * 128 + wid * 32;

  const u16* kp0 = kb + (size_t)b * 512 * 1024 + h * 64;     // K rows, stride 1024
  const u16* vp0 = vt + ((size_t)(b * 16 + h)) * 64 * 512;   // V^T rows, stride 512

  __shared__ __align__(16) u16 lK[2][64 * 64];
  __shared__ __align__(16) u16 lV[2][64 * 64];
  __shared__ __align__(16) u16 lP[4][2][16][72];

#define STAGE(bsel, k0s) do { \
  _Pragma("unroll") \
  for (int i = 0; i < 2; ++i){ \
    const int idx = i * 256 + tid; \
    const int row = idx >> 3, seg = idx & 7; \
    const int sc = ((seg ^ (row & 7)) << 3); \
    ASYNC_COPY16(kp0 + (size_t)((k0s) + row) * 1024 + sc, &lK[bsel][idx * 8]); \
    ASYNC_COPY16(vp0 + (size_t)row * 512 + (k0s) + sc,    &lV[bsel][idx * 8]); \
  } \
} while (0)

  const u16* qp = qb + ((size_t)b * 512 + q0) * 1024 + h * 64;
  s8v qf[2][2];
#pragma unroll
  for (int qt = 0; qt < 2; ++qt)
#pragma unroll
    for (int st = 0; st < 2; ++st)
      qf[qt][st] = *(const s8v*)&qp[(size_t)(qt * 16 + l15) * 1024 + st * 32 + hi * 8];

  f32x4 o[2][4];
#pragma unroll
  for (int qt = 0; qt < 2; ++qt)
#pragma unroll
    for (int mi = 0; mi < 4; ++mi) o[qt][mi] = f32x4{0.f, 0.f, 0.f, 0.f};
  float mrun[2] = {-3e38f, -3e38f}, lrun[2] = {0.f, 0.f};

  STAGE(0, 0);
  __syncthreads();

  for (int t = 0; t < 8; ++t){
    const int buf = t & 1;
    if (t < 7) STAGE(buf ^ 1, (t + 1) * 64);

    f32x4 s[2][4];
#pragma unroll
    for (int qt = 0; qt < 2; ++qt)
#pragma unroll
      for (int kt = 0; kt < 4; ++kt) s[qt][kt] = f32x4{0.f, 0.f, 0.f, 0.f};
#pragma unroll
    for (int st = 0; st < 2; ++st){
      s8v kf[4];
#pragma unroll
      for (int kt = 0; kt < 4; ++kt){
        const int row = kt * 16 + l15;
        kf[kt] = *(const s8v*)&lK[buf][row * 64 + (((st * 4 + hi) ^ (row & 7)) << 3)];
      }
#pragma unroll
      for (int qt = 0; qt < 2; ++qt)
#pragma unroll
        for (int kt = 0; kt < 4; ++kt)
          s[qt][kt] = mfma16(kf[kt], qf[qt][st], s[qt][kt]);
    }

#pragma unroll
    for (int qt = 0; qt < 2; ++qt){
      float mx = s[qt][0][0];
#pragma unroll
      for (int kt = 0; kt < 4; ++kt)
#pragma unroll
        for (int r = 0; r < 4; ++r) mx = fmaxf(mx, s[qt][kt][r]);
      mx *= 0.125f;
      mx = fmaxf(mx, __shfl_xor(mx, 16));
      mx = fmaxf(mx, __shfl_xor(mx, 32));
      const float mnew = fmaxf(mrun[qt], mx);
      const float alpha = __expf(mrun[qt] - mnew);
      mrun[qt] = mnew;
      float ps = 0.f;
#pragma unroll
      for (int kt = 0; kt < 4; ++kt){
        s4v pk;
#pragma unroll
        for (int r = 0; r < 4; ++r){
          const float p = __expf(s[qt][kt][r] * 0.125f - mnew);
          ps += p; pk[r] = (short)f2bf(p);
        }
        *(s4v*)&lP[wid][qt][l15][kt * 16 + 4 * hi] = pk;
      }
      ps += __shfl_xor(ps, 16);
      ps += __shfl_xor(ps, 32);
      lrun[qt] = lrun[qt] * alpha + ps;
#pragma unroll
      for (int mi = 0; mi < 4; ++mi)
#pragma unroll
        for (int r = 0; r < 4; ++r) o[qt][mi][r] *= alpha;
    }

#pragma unroll
    for (int ks = 0; ks < 2; ++ks){
      s8v vf[4];
#pragma unroll
      for (int mi = 0; mi < 4; ++mi){
        const int row = mi * 16 + l15;
        vf[mi] = *(const s8v*)&lV[buf][row * 64 + (((ks * 4 + hi) ^ (row & 7)) << 3)];
      }
#pragma unroll
      for (int qt = 0; qt < 2; ++qt){
        const s8v pf = *(const s8v*)&lP[wid][qt][l15][ks * 32 + 8 * hi];
#pragma unroll
        for (int mi = 0; mi < 4; ++mi)
          o[qt][mi] = mfma16(vf[mi], pf, o[qt][mi]);
      }
    }
    __syncthreads();
  }
#undef STAGE

#pragma unroll
  for (int qt = 0; qt < 2; ++qt){
    const float inv = 1.f / lrun[qt];
    u16* cp = ctx + ((size_t)b * 512 + q0 + qt * 16 + l15) * 1024 + h * 64;
#pragma unroll
    for (int mi = 0; mi < 4; ++mi)
#pragma unroll
      for (int r = 0; r < 4; ++r)
        cp[mi * 16 + 4 * hi + r] = f2bf(o[qt][mi][r] * inv);
  }
}

// ---------------------------------------------------------------------------
// Fused LN1 (in place, fp32) + LN2 -> bf16 xln + router column sums.
__global__ __launch_bounds__(256, 2) void ln12_colsum(
    float* __restrict__ t, const float* __restrict__ g1, const float* __restrict__ b1,
    const float* __restrict__ g2, const float* __restrict__ b2,
    u16* __restrict__ xln, float* __restrict__ colsum)
{
  const int b = blockIdx.y;
  const int wid = threadIdx.x >> 6, lane = threadIdx.x & 63;
  __shared__ float cacc[1024];
  for (int i = threadIdx.x; i < 1024; i += 256) cacc[i] = 0.f;
  __syncthreads();
  float acc[16];
#pragma unroll
  for (int i = 0; i < 16; ++i) acc[i] = 0.f;
  const int rbase = b * 512 + blockIdx.x * 64 + wid * 16;
  for (int rr = 0; rr < 16; ++rr){
    float* p = t + (size_t)(rbase + rr) * 1024;
    f32x4 v[4];
#pragma unroll
    for (int c = 0; c < 4; ++c) v[c] = *(const f32x4*)&p[c * 256 + lane * 4];
    float s = 0.f;
#pragma unroll
    for (int c = 0; c < 4; ++c) s += v[c][0] + v[c][1] + v[c][2] + v[c][3];
    const float mu = wave_sum(s) * (1.f / 1024.f);
    float s2 = 0.f;
#pragma unroll
    for (int c = 0; c < 4; ++c)
#pragma unroll
      for (int j = 0; j < 4; ++j){ const float d = v[c][j] - mu; s2 += d * d; }
    const float rs = rsqrtf(wave_sum(s2) * (1.f / 1024.f) + 1e-12f);
    float y1s = 0.f;
#pragma unroll
    for (int c = 0; c < 4; ++c){
      const f32x4 gg = *(const f32x4*)&g1[c * 256 + lane * 4];
      const f32x4 bb = *(const f32x4*)&b1[c * 256 + lane * 4];
#pragma unroll
      for (int j = 0; j < 4; ++j){
        v[c][j] = (v[c][j] - mu) * rs * gg[j] + bb[j];
        y1s += v[c][j];
      }
      *(f32x4*)&p[c * 256 + lane * 4] = v[c];      // attn_out (resid for down)
    }
    const float mu2 = wave_sum(y1s) * (1.f / 1024.f);
    float s22 = 0.f;
#pragma unroll
    for (int c = 0; c < 4; ++c)
#pragma unroll
      for (int j = 0; j < 4; ++j){ const float d = v[c][j] - mu2; s22 += d * d; }
    const float rs2 = rsqrtf(wave_sum(s22) * (1.f / 1024.f) + 1e-12f);
    u16* op = xln + (size_t)(rbase + rr) * 1024;
#pragma unroll
    for (int c = 0; c < 4; ++c){
      const f32x4 gg = *(const f32x4*)&g2[c * 256 + lane * 4];
      const f32x4 bb = *(const f32x4*)&b2[c * 256 + lane * 4];
      s4v ov;
#pragma unroll
      for (int j = 0; j < 4; ++j){
        const float y = (v[c][j] - mu2) * rs2 * gg[j] + bb[j];
        acc[c * 4 + j] += y;
        ov[j] = (short)f2bf(y);
      }
      *(s4v*)&op[c * 256 + lane * 4] = ov;
    }
  }
#pragma unroll
  for (int c = 0; c < 4; ++c)
#pragma unroll
    for (int j = 0; j < 4; ++j)
      atomicAdd(&cacc[c * 256 + lane * 4 + j], acc[c * 4 + j]);
  __syncthreads();
  for (int i = threadIdx.x; i < 1024; i += 256) atomicAdd(&colsum[b * 1024 + i], cacc[i]);
}

// logits[b][e] = (1/S) * sum_h colsum[b][h]*gate[h][e]; argmax -> choice.
__global__ void router_argmax(const float* __restrict__ colsum, const float* __restrict__ gate,
                              float* __restrict__ logits, int* __restrict__ choice)
{
  const int b = blockIdx.x, lane = threadIdx.x;   // 64 threads
  float pa[8];
#pragma unroll
  for (int e = 0; e < 8; ++e) pa[e] = 0.f;
  for (int it = 0; it < 16; ++it){
    const int hh = it * 64 + lane;
    const float c = colsum[b * 1024 + hh];
    const float* gp = gate + (size_t)hh * 8;
#pragma unroll
    for (int e = 0; e < 8; ++e) pa[e] += c * gp[e];
  }
#pragma unroll
  for (int e = 0; e < 8; ++e) pa[e] = wave_sum(pa[e]);
  if (lane == 0){
    float best = -3e38f; int bi = 0;
#pragma unroll
    for (int e = 0; e < 8; ++e){
      const float lg = pa[e] * (1.f / 512.f);
      logits[b * 8 + e] = lg;
      if (lg > best){ best = lg; bi = e; }   // strict > keeps first max (jnp.argmax)
    }
    choice[b] = bi;
  }
}

// ---------------------------------------------------------------------------
extern "C" void kernel_launch(void* const* d_in, const int* in_sizes, int n_in,
                              void* d_out, int out_size, void* d_ws, size_t ws_size,
                              hipStream_t stream)
{
  const float* x    = (const float*)d_in[0];
  const float* Wq   = (const float*)d_in[1];
  const float* bq   = (const float*)d_in[2];
  const float* Wk   = (const float*)d_in[3];
  const float* bk   = (const float*)d_in[4];
  const float* Wv   = (const float*)d_in[5];
  const float* bv   = (const float*)d_in[6];
  const float* Wo   = (const float*)d_in[7];
  const float* bo   = (const float*)d_in[8];
  const float* ln1g = (const float*)d_in[9];
  const float* ln1b = (const float*)d_in[10];
  const float* ln2g = (const float*)d_in[11];
  const float* ln2b = (const float*)d_in[12];
  const float* gate = (const float*)d_in[13];
  const float* Wup  = (const float*)d_in[14];
  const float* bup  = (const float*)d_in[15];
  const float* Wdn  = (const float*)d_in[16];
  const float* bdn  = (const float*)d_in[17];

  size_t off = 0;
  char* wsb = (char*)d_ws;
  auto take = [&](size_t n) -> void* {
    void* p = wsb + off; off += (n + 255) & ~(size_t)255; return p;
  };
  u16*   x_bf  = (u16*)take(8192ull * 1024 * 2);          // later: ctx
  u16*   Wqt   = (u16*)take(1024ull * 1024 * 2);          // Wqt/Wkt/Wvt contiguous
  u16*   Wkt   = (u16*)take(1024ull * 1024 * 2);
  u16*   Wvt   = (u16*)take(1024ull * 1024 * 2);
  u16*   Wot   = (u16*)take(1024ull * 1024 * 2);
  u16*   q_bf  = (u16*)take(8192ull * 1024 * 2);          // later: x_ln
  u16*   k_bf  = (u16*)take(8192ull * 1024 * 2);
  u16*   vt_bf = (u16*)take(8192ull * 1024 * 2);
  float* tmp   = (float*)take(8192ull * 1024 * 4);        // pre-LN1 -> attn_out
  u16*   Wupt  = (u16*)take(8ull * 4096 * 1024 * 2);
  u16*   Wdnt  = (u16*)take(8ull * 1024 * 4096 * 2);
  u16*   h_bf  = (u16*)take(8192ull * 4096 * 2);
  float* colsum = (float*)take(16ull * 1024 * 4);
  int*   choice = (int*)take(256);
  float* qkvb  = (float*)take(3072 * 4);                  // concat bq|bk|bv

  u16* ctx = x_bf;     // x_bf dead after QKV GEMM
  u16* xln = q_bf;     // q_bf dead after attention
  float* logits = (float*)d_out + 8388608;

  // 1. convert + transpose (+ bias concat for fused QKV)
  cvt_bf16<<<4096, 256, 0, stream>>>(x, x_bf);
  transpose_w<<<dim3(16, 16, 1), 256, 0, stream>>>(Wq,  Wqt,  1024, 1024);
  transpose_w<<<dim3(16, 16, 1), 256, 0, stream>>>(Wk,  Wkt,  1024, 1024);
  transpose_w<<<dim3(16, 16, 1), 256, 0, stream>>>(Wv,  Wvt,  1024, 1024);
  transpose_w<<<dim3(16, 16, 1), 256, 0, stream>>>(Wo,  Wot,  1024, 1024);
  transpose_w<<<dim3(64, 16, 8), 256, 0, stream>>>(Wup, Wupt, 1024, 4096);
  transpose_w<<<dim3(16, 64, 8), 256, 0, stream>>>(Wdn, Wdnt, 4096, 1024);
  hipMemcpyAsync(qkvb,        bq, 1024 * 4, hipMemcpyDeviceToDevice, stream);
  hipMemcpyAsync(qkvb + 1024, bk, 1024 * 4, hipMemcpyDeviceToDevice, stream);
  hipMemcpyAsync(qkvb + 2048, bv, 1024 * 4, hipMemcpyDeviceToDevice, stream);

  // 2. fused QKV projection (weights Wqt|Wkt|Wvt contiguous = [3072][1024])
  gemm_bt<4, true><<<dim3(64, 24, 1), 256, 0, stream>>>(x_bf, Wqt, qkvb, q_bf,
      nullptr, 8192, 3072, 1024, nullptr, 0, 0, 0, 0, 0, k_bf, vt_bf);

  // 3. attention -> ctx (reuses x_bf)
  attn_fwd<<<dim3(4, 16, 16), 256, 0, stream>>>(q_bf, k_bf, vt_bf, ctx);

  // 4. output projection + residual(x) -> tmp (fp32), then fused LN1/LN2
  gemm_bt<2, true><<<dim3(64, 8, 1), 256, 0, stream>>>(ctx, Wot, bo, tmp, x,
      8192, 1024, 1024, nullptr, 0, 0, 0, 0, 0, nullptr, nullptr);
  hipMemsetAsync(colsum, 0, 16 * 1024 * sizeof(float), stream);
  ln12_colsum<<<dim3(8, 16), 256, 0, stream>>>(tmp, ln1g, ln1b, ln2g, ln2b, xln, colsum);
  router_argmax<<<16, 64, 0, stream>>>(colsum, gate, logits, choice);

  // 5. MoE: up (gelu) then down (+attn_out residual) -> d_out
  gemm_bt<1, true><<<dim3(4, 32, 16), 256, 0, stream>>>(xln, Wupt, bup, h_bf, nullptr,
      512, 4096, 1024, choice, 512ll * 1024, 512ll * 4096, 0, 4096ll * 1024, 4096,
      nullptr, nullptr);
  gemm_bt<2, true><<<dim3(4, 8, 16), 256, 0, stream>>>(h_bf, Wdnt, bdn, d_out, tmp,
      512, 1024, 4096, choice, 512ll * 4096, 512ll * 1024, 512ll * 1024, 1024ll * 4096, 1024,
      nullptr, nullptr);
}